// Round 3
// baseline (162.233 us; speedup 1.0000x reference)
//
#include <hip/hip_runtime.h>
#include <math.h>

#define LQ 2048
#define EQ 1024
#define HQ 1024
#define DQ 512
#define VQ 32000
#define MVQ 32768

// d_out layout (floats): [out1: 32768][h_new: 1024][attn_w: 2048][prob_c: 2048]
#define OUT1_OFF 0
#define HNEW_OFF 32768
#define AW_OFF   33792
#define PC_OFF   35840

#define PSZ 2097152  // one K-split partial: 2048x1024 floats

typedef __attribute__((ext_vector_type(8))) short short8_t;
typedef __attribute__((ext_vector_type(8))) unsigned short ushort8_t;
typedef __attribute__((ext_vector_type(4))) float floatx4;

// ---------------- helpers ----------------
__device__ inline float wred(float v) {
    v += __shfl_down(v, 32);
    v += __shfl_down(v, 16);
    v += __shfl_down(v, 8);
    v += __shfl_down(v, 4);
    v += __shfl_down(v, 2);
    v += __shfl_down(v, 1);
    return v;
}
__device__ inline float wred_max(float v) {
    v = fmaxf(v, __shfl_down(v, 32));
    v = fmaxf(v, __shfl_down(v, 16));
    v = fmaxf(v, __shfl_down(v, 8));
    v = fmaxf(v, __shfl_down(v, 4));
    v = fmaxf(v, __shfl_down(v, 2));
    v = fmaxf(v, __shfl_down(v, 1));
    return v;
}
__device__ inline float sigmoidf_(float x) { return 1.0f / (1.0f + expf(-x)); }
__device__ inline unsigned short f2bf(float x) {  // RNE truncate to bf16 bits
    unsigned int u = __float_as_uint(x);
    unsigned int r = (u + 0x7fffu + ((u >> 16) & 1u)) >> 16;
    return (unsigned short)r;
}
__device__ inline float bf2f(unsigned short b) {
    return __uint_as_float(((unsigned int)b) << 16);
}

// ---------------- k_split_prep ----------------
// Blocks 0..1535: split enc (2M elems) then Wc (1M elems) into bf16 hi/lo.
// Block 1536: sel_reading with exact int32 truncation -> x2[1024:2048).
__global__ __launch_bounds__(256) void k_split_prep(
    const float* __restrict__ enc, const float* __restrict__ Wc,
    const int* __restrict__ inp, const int* __restrict__ input_seq,
    const int* __restrict__ pre_prob,
    unsigned short* __restrict__ Ah, unsigned short* __restrict__ Al,
    unsigned short* __restrict__ Bh, unsigned short* __restrict__ Bl,
    float* __restrict__ x2)
{
    __shared__ int s_cnt;
    __shared__ int s_list[LQ];
    int tid = threadIdx.x;
    if (blockIdx.x == 1536) {  // prep path
        if (tid == 0) s_cnt = 0;
        __syncthreads();
        int tok = inp[0];
        for (int l = tid; l < LQ; l += 256) {
            if (input_seq[l] == tok && pre_prob[l] != 0) {
                int p = atomicAdd(&s_cnt, 1);
                s_list[p] = l;
            }
        }
        __syncthreads();
        int nm = s_cnt;
        for (int e = tid; e < EQ; e += 256) {
            int acc = 0;
            for (int j = 0; j < nm; ++j)
                acc += (int)enc[(size_t)s_list[j] * EQ + e];
            x2[HQ + e] = (float)acc;
        }
        return;
    }
    size_t e0 = ((size_t)blockIdx.x * 256 + tid) * 8;
    const float* src;
    unsigned short *hdst, *ldst;
    size_t off;
    if (e0 < (size_t)LQ * EQ) { src = enc; hdst = Ah; ldst = Al; off = e0; }
    else { src = Wc; hdst = Bh; ldst = Bl; off = e0 - (size_t)LQ * EQ; }
    float4 v0 = *(const float4*)(src + off);
    float4 v1 = *(const float4*)(src + off + 4);
    float vv[8] = {v0.x, v0.y, v0.z, v0.w, v1.x, v1.y, v1.z, v1.w};
    ushort8_t H, L;
    #pragma unroll
    for (int k = 0; k < 8; ++k) {
        float x = vv[k];
        unsigned short hb = f2bf(x);
        H[k] = hb;
        L[k] = f2bf(x - bf2f(hb));  // exact residual
    }
    *(ushort8_t*)(hdst + off) = H;
    *(ushort8_t*)(ldst + off) = L;
}

// ---------------- k_gemm_mfma ----------------
// P_z = enc_slice @ Wc^T_slice via 3-term bf16 split (hi*hi + lo*hi + hi*lo),
// fp32 MFMA accumulate. BM=BN=128, BK=32, K-split z in {0,1} over K=512 each.
// 4 waves, each computes 64x64 (4x4 frags of 16x16x32). LDS XOR-swizzled.
__global__ __launch_bounds__(256) void k_gemm_mfma(
    const unsigned short* __restrict__ Ah, const unsigned short* __restrict__ Al,
    const unsigned short* __restrict__ Bh, const unsigned short* __restrict__ Bl,
    float* __restrict__ P)
{
    __shared__ unsigned short sm[4 * 4096];  // 4 tiles of 128x32 bf16 (8KB each)
    const int t = threadIdx.x;
    const int n0 = blockIdx.x * 128;
    const int m0 = blockIdx.y * 128;
    const int kz = blockIdx.z * 512;
    float* Pz = P + (size_t)blockIdx.z * PSZ;
    const int lane = t & 63, wid = t >> 6;
    const int wm = (wid >> 1) * 64, wn = (wid & 1) * 64;

    const unsigned short* srcs[4];
    srcs[0] = Ah + (size_t)m0 * EQ;
    srcs[1] = Al + (size_t)m0 * EQ;
    srcs[2] = Bh + (size_t)n0 * EQ;
    srcs[3] = Bl + (size_t)n0 * EQ;

    floatx4 acc[4][4];
    #pragma unroll
    for (int i = 0; i < 4; ++i)
        #pragma unroll
        for (int j = 0; j < 4; ++j)
            acc[i][j] = (floatx4){0.f, 0.f, 0.f, 0.f};

    // staging map: j=0..7 -> tile j>>1, chunk idx=(j&1)*256+t; row=idx>>2, kc=idx&3
    float4 pre[8];
    #pragma unroll
    for (int j = 0; j < 8; ++j) {
        int idx = (j & 1) * 256 + t;
        int row = idx >> 2, kc = idx & 3;
        pre[j] = *(const float4*)(srcs[j >> 1] + (size_t)row * EQ + kz + kc * 8);
    }

    for (int st = 0; st < 16; ++st) {
        #pragma unroll
        for (int j = 0; j < 8; ++j) {
            int idx = (j & 1) * 256 + t;
            int row = idx >> 2, kc = idx & 3;
            int byte = (j >> 1) * 8192 + ((row * 64 + kc * 16) ^ ((row & 7) << 4));
            *(float4*)((char*)sm + byte) = pre[j];
        }
        __syncthreads();
        if (st < 15) {  // prefetch next slab; completes under MFMA phase
            #pragma unroll
            for (int j = 0; j < 8; ++j) {
                int idx = (j & 1) * 256 + t;
                int row = idx >> 2, kc = idx & 3;
                pre[j] = *(const float4*)(srcs[j >> 1] + (size_t)row * EQ + kz +
                                          (st + 1) * 32 + kc * 8);
            }
        }
        short8_t ah[4], al[4], bh[4], bl[4];
        int rsel = lane & 15, kg = lane >> 4;
        #pragma unroll
        for (int f = 0; f < 4; ++f) {
            int rowa = wm + f * 16 + rsel;
            int ba = (rowa * 64 + kg * 16) ^ ((rowa & 7) << 4);
            ah[f] = *(const short8_t*)((const char*)sm + ba);
            al[f] = *(const short8_t*)((const char*)sm + 8192 + ba);
            int rowb = wn + f * 16 + rsel;
            int bb = (rowb * 64 + kg * 16) ^ ((rowb & 7) << 4);
            bh[f] = *(const short8_t*)((const char*)sm + 16384 + bb);
            bl[f] = *(const short8_t*)((const char*)sm + 24576 + bb);
        }
        #pragma unroll
        for (int i = 0; i < 4; ++i)
            #pragma unroll
            for (int j = 0; j < 4; ++j) {
                acc[i][j] = __builtin_amdgcn_mfma_f32_16x16x32_bf16(
                    ah[i], bh[j], acc[i][j], 0, 0, 0);
                acc[i][j] = __builtin_amdgcn_mfma_f32_16x16x32_bf16(
                    al[i], bh[j], acc[i][j], 0, 0, 0);
                acc[i][j] = __builtin_amdgcn_mfma_f32_16x16x32_bf16(
                    ah[i], bl[j], acc[i][j], 0, 0, 0);
            }
        __syncthreads();
    }
    // C/D layout: col = lane&15, row = (lane>>4)*4 + reg  [m89-verified]
    #pragma unroll
    for (int i = 0; i < 4; ++i)
        #pragma unroll
        for (int j = 0; j < 4; ++j) {
            int row = m0 + wm + i * 16 + (lane >> 4) * 4;
            int col = n0 + wn + j * 16 + (lane & 15);
            #pragma unroll
            for (int r = 0; r < 4; ++r)
                Pz[(size_t)(row + r) * HQ + col] = acc[i][j][r];
        }
}

// ---------------- k_attn ----------------
// logits[r] = attn_W[r,:] . [emb_row | hidden] + attn_b[r]. Also zeroes aa.
__global__ __launch_bounds__(256) void k_attn(
    const float* __restrict__ W, const float* __restrict__ b,
    const int* __restrict__ inp, const float* __restrict__ emb,
    const float* __restrict__ hidden, float* __restrict__ logits,
    float* __restrict__ aa)
{
    int t = threadIdx.x;
    if (blockIdx.x < 4) aa[blockIdx.x * 256 + t] = 0.0f;
    int warp = t >> 6, lane = t & 63;
    int r = blockIdx.x * 4 + warp;
    int tok = inp[0];
    int ei = (tok >= VQ) ? 2 : tok;
    const float4* Wr = (const float4*)(W + (size_t)r * 1536);
    const float4* e4 = (const float4*)(emb + (size_t)ei * DQ);
    const float4* h4 = (const float4*)hidden;
    float acc = 0.0f;
    #pragma unroll
    for (int i = 0; i < 6; ++i) {
        int idx = lane + i * 64;
        float4 x = (idx < 128) ? e4[idx] : h4[idx - 128];
        float4 w = Wr[idx];
        acc += w.x * x.x + w.y * x.y + w.z * x.z + w.w * x.w;
    }
    acc = wred(acc);
    if (lane == 0) logits[r] = acc + b[r];
}

// ---------------- k_attn_sm_apply ----------------
// Per-block softmax stats (identical across blocks), write aw, aa += w.enc
__global__ __launch_bounds__(256) void k_attn_sm_apply(
    const float* __restrict__ logits, const float* __restrict__ enc,
    float* __restrict__ aa, float* __restrict__ aw_out)
{
    __shared__ float sred[4];
    __shared__ float s_w[128];
    int tid = threadIdx.x, wid = tid >> 6, lane = tid & 63;
    float m = -3.4e38f;
    for (int i = tid; i < LQ; i += 256) m = fmaxf(m, logits[i]);
    m = wred_max(m);
    if (lane == 0) sred[wid] = m;
    __syncthreads();
    if (tid == 0)
        sred[0] = fmaxf(fmaxf(sred[0], sred[1]), fmaxf(sred[2], sred[3]));
    __syncthreads();
    m = sred[0];
    __syncthreads();
    float s = 0.0f;
    for (int i = tid; i < LQ; i += 256) s += expf(logits[i] - m);
    s = wred(s);
    if (lane == 0) sred[wid] = s;
    __syncthreads();
    if (tid == 0) sred[0] = sred[0] + sred[1] + sred[2] + sred[3];
    __syncthreads();
    s = sred[0];
    int l0 = blockIdx.y * 128;
    if (tid < 128) {
        float w = expf(logits[l0 + tid] - m) / s;
        s_w[tid] = w;
        if (blockIdx.x == 0) aw_out[l0 + tid] = w;
    }
    __syncthreads();
    int e = blockIdx.x * 256 + tid;
    float acc = 0.0f;
    for (int l = 0; l < 128; ++l)
        acc = fmaf(s_w[l], enc[(size_t)(l0 + l) * EQ + e], acc);
    atomicAdd(&aa[e], acc);
}

// ---------------- k_comb ----------------
__global__ __launch_bounds__(256) void k_comb(
    const float* __restrict__ W, const float* __restrict__ b,
    const int* __restrict__ inp, const float* __restrict__ emb,
    const float* __restrict__ aa, float* __restrict__ x2)
{
    int warp = threadIdx.x >> 6, lane = threadIdx.x & 63;
    int r = blockIdx.x * 4 + warp;
    int tok = inp[0];
    int ei = (tok >= VQ) ? 2 : tok;
    const float4* Wr = (const float4*)(W + (size_t)r * 1536);
    const float4* e4 = (const float4*)(emb + (size_t)ei * DQ);
    const float4* a4 = (const float4*)aa;
    float acc = 0.0f;
    #pragma unroll
    for (int i = 0; i < 6; ++i) {
        int idx = lane + i * 64;
        float4 x = (idx < 128) ? e4[idx] : a4[idx - 128];
        float4 w = Wr[idx];
        acc += w.x * x.x + w.y * x.y + w.z * x.z + w.w * x.w;
    }
    acc = wred(acc);
    if (lane == 0) x2[r] = fmaxf(acc + b[r], 0.0f);
}

// ---------------- k_gru ----------------
// Fused: warp handles gate index i; computes all 6 dots, gates, h_new.
__global__ __launch_bounds__(256) void k_gru(
    const float* __restrict__ W_ih, const float* __restrict__ W_hh,
    const float* __restrict__ b_ih, const float* __restrict__ b_hh,
    const float* __restrict__ x2, const float* __restrict__ h,
    float* __restrict__ hnew, float* __restrict__ out_h)
{
    int warp = threadIdx.x >> 6, lane = threadIdx.x & 63;
    int i = blockIdx.x * 4 + warp;
    const float4* xv = (const float4*)x2;
    const float4* hv = (const float4*)h;
    const float4* Wr = (const float4*)(W_ih + (size_t)i * 2048);
    const float4* Wz = (const float4*)(W_ih + (size_t)(HQ + i) * 2048);
    const float4* Wn = (const float4*)(W_ih + (size_t)(2 * HQ + i) * 2048);
    const float4* Ur = (const float4*)(W_hh + (size_t)i * 1024);
    const float4* Uz = (const float4*)(W_hh + (size_t)(HQ + i) * 1024);
    const float4* Un = (const float4*)(W_hh + (size_t)(2 * HQ + i) * 1024);
    float ar = 0, az = 0, an = 0, br = 0, bz = 0, bn = 0;
    #pragma unroll
    for (int c = 0; c < 8; ++c) {
        int idx = lane + c * 64;
        float4 x = xv[idx];
        float4 w = Wr[idx]; ar += w.x*x.x + w.y*x.y + w.z*x.z + w.w*x.w;
        w = Wz[idx];        az += w.x*x.x + w.y*x.y + w.z*x.z + w.w*x.w;
        w = Wn[idx];        an += w.x*x.x + w.y*x.y + w.z*x.z + w.w*x.w;
    }
    #pragma unroll
    for (int c = 0; c < 4; ++c) {
        int idx = lane + c * 64;
        float4 x = hv[idx];
        float4 w = Ur[idx]; br += w.x*x.x + w.y*x.y + w.z*x.z + w.w*x.w;
        w = Uz[idx];        bz += w.x*x.x + w.y*x.y + w.z*x.z + w.w*x.w;
        w = Un[idx];        bn += w.x*x.x + w.y*x.y + w.z*x.z + w.w*x.w;
    }
    ar = wred(ar); az = wred(az); an = wred(an);
    br = wred(br); bz = wred(bz); bn = wred(bn);
    if (lane == 0) {
        float r = sigmoidf_(ar + b_ih[i] + br + b_hh[i]);
        float z = sigmoidf_(az + b_ih[HQ + i] + bz + b_hh[HQ + i]);
        float n = tanhf(an + b_ih[2 * HQ + i] + r * (bn + b_hh[2 * HQ + i]));
        float hn = (1.0f - z) * n + z * h[i];
        hnew[i] = hn;
        out_h[i] = hn;
    }
}

// ---------------- k_scores ----------------
// r < VQ:  score[r] = Wo_W[r,:] . hnew + Wo_b[r]
// r >= VQ: l=r-VQ: score[VQ+l] = sum_h tanh(P0[l][h]+P1[l][h]+Wc_b[h])*hnew[h]
__global__ __launch_bounds__(256) void k_scores(
    const float* __restrict__ Wo_W, const float* __restrict__ Wo_b,
    const float* __restrict__ P, const float* __restrict__ Wc_b,
    const float* __restrict__ hnew, float* __restrict__ score)
{
    int warp = threadIdx.x >> 6, lane = threadIdx.x & 63;
    int r = blockIdx.x * 4 + warp;
    const float4* hv = (const float4*)hnew;
    float acc = 0.0f;
    if (r < VQ) {
        const float4* Wr = (const float4*)(Wo_W + (size_t)r * HQ);
        #pragma unroll
        for (int i = 0; i < 4; ++i) {
            int idx = lane + i * 64;
            float4 w = Wr[idx], x = hv[idx];
            acc += w.x * x.x + w.y * x.y + w.z * x.z + w.w * x.w;
        }
        acc = wred(acc);
        if (lane == 0) score[r] = acc + Wo_b[r];
    } else {
        int l = r - VQ;
        const float4* P0 = (const float4*)(P + (size_t)l * HQ);
        const float4* P1 = (const float4*)(P + (size_t)PSZ + (size_t)l * HQ);
        #pragma unroll
        for (int i = 0; i < 4; ++i) {
            int idx = lane + i * 64;
            float4 a = P0[idx], b = P1[idx];
            float4 bb = *(const float4*)(Wc_b + idx * 4);
            float4 x = hv[idx];
            acc += tanhf(a.x + b.x + bb.x) * x.x + tanhf(a.y + b.y + bb.y) * x.y +
                   tanhf(a.z + b.z + bb.z) * x.z + tanhf(a.w + b.w + bb.w) * x.w;
        }
        acc = wred(acc);
        if (lane == 0) score[VQ + l] = acc;
    }
}

// ---------------- k_probs ----------------
// Per-block recompute of max/sum over the 34048 scores (deterministic,
// identical in every block), then write prob_g / zeros / prob_c.
__global__ __launch_bounds__(256) void k_probs(
    const float* __restrict__ score, float* __restrict__ out1,
    float* __restrict__ out_pc)
{
    __shared__ float sred[4];
    const int N = VQ + LQ;
    int tid = threadIdx.x, wid = tid >> 6, lane = tid & 63;
    float m = -3.4e38f;
    for (int i = tid; i < N; i += 256) m = fmaxf(m, score[i]);
    m = wred_max(m);
    if (lane == 0) sred[wid] = m;
    __syncthreads();
    if (tid == 0)
        sred[0] = fmaxf(fmaxf(sred[0], sred[1]), fmaxf(sred[2], sred[3]));
    __syncthreads();
    m = sred[0];
    __syncthreads();
    float s = 0.0f;
    for (int i = tid; i < N; i += 256) s += expf(score[i] - m);
    s = wred(s);
    if (lane == 0) sred[wid] = s;
    __syncthreads();
    if (tid == 0) sred[0] = sred[0] + sred[1] + sred[2] + sred[3];
    __syncthreads();
    s = sred[0];
    int i = blockIdx.x * 256 + tid;
    if (i < MVQ) {
        out1[i] = (i < VQ) ? expf(score[i] - m) / s : 0.0f;
    } else {
        int l = i - MVQ;
        out_pc[l] = expf(score[VQ + l] - m) / s;
    }
}

// ---------------- k_scatter ----------------
__global__ __launch_bounds__(256) void k_scatter(
    const int* __restrict__ input_seq, const float* __restrict__ pc,
    float* __restrict__ out1)
{
    int l = blockIdx.x * 256 + threadIdx.x;
    atomicAdd(&out1[input_seq[l]], pc[l]);
}

// ---------------- k_log ----------------
__global__ __launch_bounds__(256) void k_log(float* __restrict__ out1)
{
    int i = blockIdx.x * 256 + threadIdx.x;
    float v = out1[i];
    if (i == 2 || v == 0.0f) v = 1e-9f;
    out1[i] = logf(v);
}

// ---------------- host launch ----------------
extern "C" void kernel_launch(void* const* d_in, const int* in_sizes, int n_in,
                              void* d_out, int out_size, void* d_ws, size_t ws_size,
                              hipStream_t stream) {
    const int*   inp       = (const int*)  d_in[0];
    const float* hidden    = (const float*)d_in[1];
    const float* enc       = (const float*)d_in[2];
    const int*   input_seq = (const int*)  d_in[3];
    const int*   pre_prob  = (const int*)  d_in[4];
    const float* emb       = (const float*)d_in[5];
    const float* attn_W    = (const float*)d_in[6];
    const float* attn_b    = (const float*)d_in[7];
    const float* comb_W    = (const float*)d_in[8];
    const float* comb_b    = (const float*)d_in[9];
    const float* W_ih      = (const float*)d_in[10];
    const float* W_hh      = (const float*)d_in[11];
    const float* b_ih      = (const float*)d_in[12];
    const float* b_hh      = (const float*)d_in[13];
    const float* Wo_W      = (const float*)d_in[14];
    const float* Wo_b      = (const float*)d_in[15];
    const float* Wc_W      = (const float*)d_in[16];
    const float* Wc_b      = (const float*)d_in[17];

    float* out = (float*)d_out;

    // ws layout: [Ah 2M us][Al 2M us][Bh 1M us][Bl 1M us][P 2*2M f][smalls]
    unsigned short* Ah = (unsigned short*)d_ws;
    unsigned short* Al = Ah + (size_t)LQ * EQ;
    unsigned short* Bh = Al + (size_t)LQ * EQ;
    unsigned short* Bl = Bh + (size_t)HQ * EQ;
    float* P      = (float*)(Bl + (size_t)HQ * EQ);
    float* x2     = P + 2 * (size_t)PSZ;   // 2048 (comb out | sel_reading)
    float* hnew   = x2 + 2048;             // 1024
    float* logits = hnew + 1024;           // 2048
    float* aa     = logits + 2048;         // 1024
    float* score  = aa + 1024;             // 34048

    k_split_prep<<<1537, 256, 0, stream>>>(enc, Wc_W, inp, input_seq, pre_prob,
                                           Ah, Al, Bh, Bl, x2);
    k_gemm_mfma<<<dim3(HQ / 128, LQ / 128, 2), 256, 0, stream>>>(Ah, Al, Bh, Bl,
                                                                 P);
    k_attn<<<LQ / 4, 256, 0, stream>>>(attn_W, attn_b, inp, emb, hidden,
                                       logits, aa);
    k_attn_sm_apply<<<dim3(EQ / 256, 16), 256, 0, stream>>>(logits, enc, aa,
                                                            out + AW_OFF);
    k_comb<<<HQ / 4, 256, 0, stream>>>(comb_W, comb_b, inp, emb, aa, x2);
    k_gru<<<HQ / 4, 256, 0, stream>>>(W_ih, W_hh, b_ih, b_hh, x2, hidden,
                                      hnew, out + HNEW_OFF);
    k_scores<<<(VQ + LQ) / 4, 256, 0, stream>>>(Wo_W, Wo_b, P, Wc_b, hnew,
                                                score);
    k_probs<<<(MVQ + LQ) / 256, 256, 0, stream>>>(score, out + OUT1_OFF,
                                                  out + PC_OFF);
    k_scatter<<<LQ / 256, 256, 0, stream>>>(input_seq, out + PC_OFF,
                                            out + OUT1_OFF);
    k_log<<<MVQ / 256, 256, 0, stream>>>(out + OUT1_OFF);
}

// Round 4
// 131.808 us; speedup vs baseline: 1.2308x; 1.2308x over previous
//
#include <hip/hip_runtime.h>
#include <math.h>

#define LQ 2048
#define EQ 1024
#define HQ 1024
#define DQ 512
#define VQ 32000
#define MVQ 32768

// d_out layout (floats): [out1: 32768][h_new: 1024][attn_w: 2048][prob_c: 2048]
#define OUT1_OFF 0
#define HNEW_OFF 32768
#define AW_OFF   33792
#define PC_OFF   35840

#define PSZ 2097152  // one K-split partial: 2048x1024 floats

typedef __attribute__((ext_vector_type(8))) short short8_t;
typedef __attribute__((ext_vector_type(8))) unsigned short ushort8_t;
typedef __attribute__((ext_vector_type(4))) float floatx4;

// ---------------- helpers ----------------
__device__ inline float wred(float v) {
    v += __shfl_down(v, 32);
    v += __shfl_down(v, 16);
    v += __shfl_down(v, 8);
    v += __shfl_down(v, 4);
    v += __shfl_down(v, 2);
    v += __shfl_down(v, 1);
    return v;
}
__device__ inline float wred_max(float v) {
    v = fmaxf(v, __shfl_down(v, 32));
    v = fmaxf(v, __shfl_down(v, 16));
    v = fmaxf(v, __shfl_down(v, 8));
    v = fmaxf(v, __shfl_down(v, 4));
    v = fmaxf(v, __shfl_down(v, 2));
    v = fmaxf(v, __shfl_down(v, 1));
    return v;
}
__device__ inline float sigmoidf_(float x) { return 1.0f / (1.0f + expf(-x)); }
__device__ inline unsigned short f2bf(float x) {  // RNE to bf16 bits
    unsigned int u = __float_as_uint(x);
    unsigned int r = (u + 0x7fffu + ((u >> 16) & 1u)) >> 16;
    return (unsigned short)r;
}
__device__ inline float bf2f(unsigned short b) {
    return __uint_as_float(((unsigned int)b) << 16);
}
// async global->LDS, 16B per lane; LDS dest is wave-uniform base + lane*16
__device__ __forceinline__ void gload16(const unsigned short* g,
                                        unsigned short* l) {
    __builtin_amdgcn_global_load_lds(
        (const __attribute__((address_space(1))) unsigned int*)g,
        (__attribute__((address_space(3))) unsigned int*)l, 16, 0, 0);
}

// ---------------- k_split_prep ----------------
// Blocks 0..1535: split enc (2M elems) then Wc (1M elems) into bf16 hi/lo.
// Block 1536: sel_reading with exact int32 truncation -> x2[1024:2048).
__global__ __launch_bounds__(256) void k_split_prep(
    const float* __restrict__ enc, const float* __restrict__ Wc,
    const int* __restrict__ inp, const int* __restrict__ input_seq,
    const int* __restrict__ pre_prob,
    unsigned short* __restrict__ Ah, unsigned short* __restrict__ Al,
    unsigned short* __restrict__ Bh, unsigned short* __restrict__ Bl,
    float* __restrict__ x2)
{
    __shared__ int s_cnt;
    __shared__ int s_list[LQ];
    int tid = threadIdx.x;
    if (blockIdx.x == 1536) {  // prep path
        if (tid == 0) s_cnt = 0;
        __syncthreads();
        int tok = inp[0];
        for (int l = tid; l < LQ; l += 256) {
            if (input_seq[l] == tok && pre_prob[l] != 0) {
                int p = atomicAdd(&s_cnt, 1);
                s_list[p] = l;
            }
        }
        __syncthreads();
        int nm = s_cnt;
        for (int e = tid; e < EQ; e += 256) {
            int acc = 0;
            for (int j = 0; j < nm; ++j)
                acc += (int)enc[(size_t)s_list[j] * EQ + e];
            x2[HQ + e] = (float)acc;
        }
        return;
    }
    size_t e0 = ((size_t)blockIdx.x * 256 + tid) * 8;
    const float* src;
    unsigned short *hdst, *ldst;
    size_t off;
    if (e0 < (size_t)LQ * EQ) { src = enc; hdst = Ah; ldst = Al; off = e0; }
    else { src = Wc; hdst = Bh; ldst = Bl; off = e0 - (size_t)LQ * EQ; }
    float4 v0 = *(const float4*)(src + off);
    float4 v1 = *(const float4*)(src + off + 4);
    float vv[8] = {v0.x, v0.y, v0.z, v0.w, v1.x, v1.y, v1.z, v1.w};
    ushort8_t H, L;
    #pragma unroll
    for (int k = 0; k < 8; ++k) {
        float x = vv[k];
        unsigned short hb = f2bf(x);
        H[k] = hb;
        L[k] = f2bf(x - bf2f(hb));  // exact residual
    }
    *(ushort8_t*)(hdst + off) = H;
    *(ushort8_t*)(ldst + off) = L;
}

// ---------------- k_gemm_mfma ----------------
// P_z = enc_slice @ Wc^T_slice via 3-term bf16 split (hi*hi + lo*hi + hi*lo),
// m97 structure: global_load_lds(16B) staging, linear LDS + source-side XOR
// swizzle (chunk ^= row&7), BK=64, 128x128 tile, K-split z in {0,1}.
// 4 waves; wave w stages tile w (Ah,Al,Bh,Bl) and computes a 64x64 quadrant.
__global__ __launch_bounds__(256, 2) void k_gemm_mfma(
    const unsigned short* __restrict__ Ah, const unsigned short* __restrict__ Al,
    const unsigned short* __restrict__ Bh, const unsigned short* __restrict__ Bl,
    float* __restrict__ P)
{
    // 4 tiles x 128 rows x 64 bf16 = 64 KB -> 2 blocks/CU
    __shared__ unsigned short sm[4 * 8192];
    const int t = threadIdx.x;
    const int lane = t & 63, wid = t >> 6;
    const int n0 = blockIdx.x * 128;
    const int m0 = blockIdx.y * 128;
    const int kz = blockIdx.z * 512;  // K element offset
    float* Pz = P + (size_t)blockIdx.z * PSZ;

    const unsigned short* tsrc =
        (wid == 0) ? Ah + (size_t)m0 * EQ :
        (wid == 1) ? Al + (size_t)m0 * EQ :
        (wid == 2) ? Bh + (size_t)n0 * EQ :
                     Bl + (size_t)n0 * EQ;
    unsigned short* tdst = sm + wid * 8192;

    const int srow = lane >> 3;   // row within 8-row staging call
    const int schunk = lane & 7;  // 16B chunk within row
    const int wm = (wid >> 1) * 64, wn = (wid & 1) * 64;
    const int fr = lane & 15, kg = lane >> 4;

    floatx4 acc[4][4];
    #pragma unroll
    for (int i = 0; i < 4; ++i)
        #pragma unroll
        for (int j = 0; j < 4; ++j)
            acc[i][j] = (floatx4){0.f, 0.f, 0.f, 0.f};

    for (int s = 0; s < 8; ++s) {
        // ---- stage: 16 async 1KB calls; LDS linear, source pre-swizzled ----
        #pragma unroll
        for (int c = 0; c < 16; ++c) {
            int row = c * 8 + srow;
            int gch = schunk ^ (row & 7);
            gload16(tsrc + (size_t)row * EQ + kz + s * 64 + gch * 8,
                    tdst + c * 512);
        }
        __syncthreads();  // compiler drains vmcnt(0) before barrier
        // ---- compute: 2 K-halves x 16 frag-pairs x 3 terms = 96 MFMA ----
        #pragma unroll
        for (int kk = 0; kk < 2; ++kk) {
            short8_t fah[4], fal[4], fbh[4], fbl[4];
            #pragma unroll
            for (int f = 0; f < 4; ++f) {
                int rowa = wm + f * 16 + fr;
                int ba = rowa * 128 + ((kk * 4 + kg) ^ (rowa & 7)) * 16;
                fah[f] = *(const short8_t*)((const char*)sm + ba);
                fal[f] = *(const short8_t*)((const char*)sm + 16384 + ba);
                int rowb = wn + f * 16 + fr;
                int bb = rowb * 128 + ((kk * 4 + kg) ^ (rowb & 7)) * 16;
                fbh[f] = *(const short8_t*)((const char*)sm + 32768 + bb);
                fbl[f] = *(const short8_t*)((const char*)sm + 49152 + bb);
            }
            #pragma unroll
            for (int i = 0; i < 4; ++i)
                #pragma unroll
                for (int j = 0; j < 4; ++j) {
                    acc[i][j] = __builtin_amdgcn_mfma_f32_16x16x32_bf16(
                        fah[i], fbh[j], acc[i][j], 0, 0, 0);
                    acc[i][j] = __builtin_amdgcn_mfma_f32_16x16x32_bf16(
                        fal[i], fbh[j], acc[i][j], 0, 0, 0);
                    acc[i][j] = __builtin_amdgcn_mfma_f32_16x16x32_bf16(
                        fah[i], fbl[j], acc[i][j], 0, 0, 0);
                }
        }
        __syncthreads();
    }
    // C/D layout: col = lane&15, row = (lane>>4)*4 + reg  [m89-verified]
    #pragma unroll
    for (int i = 0; i < 4; ++i)
        #pragma unroll
        for (int j = 0; j < 4; ++j) {
            int row = m0 + wm + i * 16 + kg * 4;
            int col = n0 + wn + j * 16 + fr;
            #pragma unroll
            for (int r = 0; r < 4; ++r)
                Pz[(size_t)(row + r) * HQ + col] = acc[i][j][r];
        }
}

// ---------------- k_attn ----------------
// logits[r] = attn_W[r,:] . [emb_row | hidden] + attn_b[r]. Also zeroes aa.
__global__ __launch_bounds__(256) void k_attn(
    const float* __restrict__ W, const float* __restrict__ b,
    const int* __restrict__ inp, const float* __restrict__ emb,
    const float* __restrict__ hidden, float* __restrict__ logits,
    float* __restrict__ aa)
{
    int t = threadIdx.x;
    if (blockIdx.x < 4) aa[blockIdx.x * 256 + t] = 0.0f;
    int warp = t >> 6, lane = t & 63;
    int r = blockIdx.x * 4 + warp;
    int tok = inp[0];
    int ei = (tok >= VQ) ? 2 : tok;
    const float4* Wr = (const float4*)(W + (size_t)r * 1536);
    const float4* e4 = (const float4*)(emb + (size_t)ei * DQ);
    const float4* h4 = (const float4*)hidden;
    float acc = 0.0f;
    #pragma unroll
    for (int i = 0; i < 6; ++i) {
        int idx = lane + i * 64;
        float4 x = (idx < 128) ? e4[idx] : h4[idx - 128];
        float4 w = Wr[idx];
        acc += w.x * x.x + w.y * x.y + w.z * x.z + w.w * x.w;
    }
    acc = wred(acc);
    if (lane == 0) logits[r] = acc + b[r];
}

// ---------------- k_attn_sm_apply ----------------
// Per-block softmax stats (identical across blocks), write aw, aa += w.enc
__global__ __launch_bounds__(256) void k_attn_sm_apply(
    const float* __restrict__ logits, const float* __restrict__ enc,
    float* __restrict__ aa, float* __restrict__ aw_out)
{
    __shared__ float sred[4];
    __shared__ float s_w[128];
    int tid = threadIdx.x, wid = tid >> 6, lane = tid & 63;
    float m = -3.4e38f;
    for (int i = tid; i < LQ; i += 256) m = fmaxf(m, logits[i]);
    m = wred_max(m);
    if (lane == 0) sred[wid] = m;
    __syncthreads();
    if (tid == 0)
        sred[0] = fmaxf(fmaxf(sred[0], sred[1]), fmaxf(sred[2], sred[3]));
    __syncthreads();
    m = sred[0];
    __syncthreads();
    float s = 0.0f;
    for (int i = tid; i < LQ; i += 256) s += expf(logits[i] - m);
    s = wred(s);
    if (lane == 0) sred[wid] = s;
    __syncthreads();
    if (tid == 0) sred[0] = sred[0] + sred[1] + sred[2] + sred[3];
    __syncthreads();
    s = sred[0];
    int l0 = blockIdx.y * 128;
    if (tid < 128) {
        float w = expf(logits[l0 + tid] - m) / s;
        s_w[tid] = w;
        if (blockIdx.x == 0) aw_out[l0 + tid] = w;
    }
    __syncthreads();
    int e = blockIdx.x * 256 + tid;
    float acc = 0.0f;
    for (int l = 0; l < 128; ++l)
        acc = fmaf(s_w[l], enc[(size_t)(l0 + l) * EQ + e], acc);
    atomicAdd(&aa[e], acc);
}

// ---------------- k_comb ----------------
__global__ __launch_bounds__(256) void k_comb(
    const float* __restrict__ W, const float* __restrict__ b,
    const int* __restrict__ inp, const float* __restrict__ emb,
    const float* __restrict__ aa, float* __restrict__ x2)
{
    int warp = threadIdx.x >> 6, lane = threadIdx.x & 63;
    int r = blockIdx.x * 4 + warp;
    int tok = inp[0];
    int ei = (tok >= VQ) ? 2 : tok;
    const float4* Wr = (const float4*)(W + (size_t)r * 1536);
    const float4* e4 = (const float4*)(emb + (size_t)ei * DQ);
    const float4* a4 = (const float4*)aa;
    float acc = 0.0f;
    #pragma unroll
    for (int i = 0; i < 6; ++i) {
        int idx = lane + i * 64;
        float4 x = (idx < 128) ? e4[idx] : a4[idx - 128];
        float4 w = Wr[idx];
        acc += w.x * x.x + w.y * x.y + w.z * x.z + w.w * x.w;
    }
    acc = wred(acc);
    if (lane == 0) x2[r] = fmaxf(acc + b[r], 0.0f);
}

// ---------------- k_gru ----------------
// Fused: warp handles gate index i; computes all 6 dots, gates, h_new.
__global__ __launch_bounds__(256) void k_gru(
    const float* __restrict__ W_ih, const float* __restrict__ W_hh,
    const float* __restrict__ b_ih, const float* __restrict__ b_hh,
    const float* __restrict__ x2, const float* __restrict__ h,
    float* __restrict__ hnew, float* __restrict__ out_h)
{
    int warp = threadIdx.x >> 6, lane = threadIdx.x & 63;
    int i = blockIdx.x * 4 + warp;
    const float4* xv = (const float4*)x2;
    const float4* hv = (const float4*)h;
    const float4* Wr = (const float4*)(W_ih + (size_t)i * 2048);
    const float4* Wz = (const float4*)(W_ih + (size_t)(HQ + i) * 2048);
    const float4* Wn = (const float4*)(W_ih + (size_t)(2 * HQ + i) * 2048);
    const float4* Ur = (const float4*)(W_hh + (size_t)i * 1024);
    const float4* Uz = (const float4*)(W_hh + (size_t)(HQ + i) * 1024);
    const float4* Un = (const float4*)(W_hh + (size_t)(2 * HQ + i) * 1024);
    float ar = 0, az = 0, an = 0, br = 0, bz = 0, bn = 0;
    #pragma unroll
    for (int c = 0; c < 8; ++c) {
        int idx = lane + c * 64;
        float4 x = xv[idx];
        float4 w = Wr[idx]; ar += w.x*x.x + w.y*x.y + w.z*x.z + w.w*x.w;
        w = Wz[idx];        az += w.x*x.x + w.y*x.y + w.z*x.z + w.w*x.w;
        w = Wn[idx];        an += w.x*x.x + w.y*x.y + w.z*x.z + w.w*x.w;
    }
    #pragma unroll
    for (int c = 0; c < 4; ++c) {
        int idx = lane + c * 64;
        float4 x = hv[idx];
        float4 w = Ur[idx]; br += w.x*x.x + w.y*x.y + w.z*x.z + w.w*x.w;
        w = Uz[idx];        bz += w.x*x.x + w.y*x.y + w.z*x.z + w.w*x.w;
        w = Un[idx];        bn += w.x*x.x + w.y*x.y + w.z*x.z + w.w*x.w;
    }
    ar = wred(ar); az = wred(az); an = wred(an);
    br = wred(br); bz = wred(bz); bn = wred(bn);
    if (lane == 0) {
        float r = sigmoidf_(ar + b_ih[i] + br + b_hh[i]);
        float z = sigmoidf_(az + b_ih[HQ + i] + bz + b_hh[HQ + i]);
        float n = tanhf(an + b_ih[2 * HQ + i] + r * (bn + b_hh[2 * HQ + i]));
        float hn = (1.0f - z) * n + z * h[i];
        hnew[i] = hn;
        out_h[i] = hn;
    }
}

// ---------------- k_scores ----------------
// r < VQ:  score[r] = Wo_W[r,:] . hnew + Wo_b[r]
// r >= VQ: l=r-VQ: score[VQ+l] = sum_h tanh(P0[l][h]+P1[l][h]+Wc_b[h])*hnew[h]
__global__ __launch_bounds__(256) void k_scores(
    const float* __restrict__ Wo_W, const float* __restrict__ Wo_b,
    const float* __restrict__ P, const float* __restrict__ Wc_b,
    const float* __restrict__ hnew, float* __restrict__ score)
{
    int warp = threadIdx.x >> 6, lane = threadIdx.x & 63;
    int r = blockIdx.x * 4 + warp;
    const float4* hv = (const float4*)hnew;
    float acc = 0.0f;
    if (r < VQ) {
        const float4* Wr = (const float4*)(Wo_W + (size_t)r * HQ);
        #pragma unroll
        for (int i = 0; i < 4; ++i) {
            int idx = lane + i * 64;
            float4 w = Wr[idx], x = hv[idx];
            acc += w.x * x.x + w.y * x.y + w.z * x.z + w.w * x.w;
        }
        acc = wred(acc);
        if (lane == 0) score[r] = acc + Wo_b[r];
    } else {
        int l = r - VQ;
        const float4* P0 = (const float4*)(P + (size_t)l * HQ);
        const float4* P1 = (const float4*)(P + (size_t)PSZ + (size_t)l * HQ);
        #pragma unroll
        for (int i = 0; i < 4; ++i) {
            int idx = lane + i * 64;
            float4 a = P0[idx], b = P1[idx];
            float4 bb = *(const float4*)(Wc_b + idx * 4);
            float4 x = hv[idx];
            acc += tanhf(a.x + b.x + bb.x) * x.x + tanhf(a.y + b.y + bb.y) * x.y +
                   tanhf(a.z + b.z + bb.z) * x.z + tanhf(a.w + b.w + bb.w) * x.w;
        }
        acc = wred(acc);
        if (lane == 0) score[VQ + l] = acc;
    }
}

// ---------------- k_probs ----------------
// Per-block recompute of max/sum over the 34048 scores (deterministic,
// identical in every block), then write prob_g / zeros / prob_c.
__global__ __launch_bounds__(256) void k_probs(
    const float* __restrict__ score, float* __restrict__ out1,
    float* __restrict__ out_pc)
{
    __shared__ float sred[4];
    const int N = VQ + LQ;
    int tid = threadIdx.x, wid = tid >> 6, lane = tid & 63;
    float m = -3.4e38f;
    for (int i = tid; i < N; i += 256) m = fmaxf(m, score[i]);
    m = wred_max(m);
    if (lane == 0) sred[wid] = m;
    __syncthreads();
    if (tid == 0)
        sred[0] = fmaxf(fmaxf(sred[0], sred[1]), fmaxf(sred[2], sred[3]));
    __syncthreads();
    m = sred[0];
    __syncthreads();
    float s = 0.0f;
    for (int i = tid; i < N; i += 256) s += expf(score[i] - m);
    s = wred(s);
    if (lane == 0) sred[wid] = s;
    __syncthreads();
    if (tid == 0) sred[0] = sred[0] + sred[1] + sred[2] + sred[3];
    __syncthreads();
    s = sred[0];
    int i = blockIdx.x * 256 + tid;
    if (i < MVQ) {
        out1[i] = (i < VQ) ? expf(score[i] - m) / s : 0.0f;
    } else {
        int l = i - MVQ;
        out_pc[l] = expf(score[VQ + l] - m) / s;
    }
}

// ---------------- k_scatter ----------------
__global__ __launch_bounds__(256) void k_scatter(
    const int* __restrict__ input_seq, const float* __restrict__ pc,
    float* __restrict__ out1)
{
    int l = blockIdx.x * 256 + threadIdx.x;
    atomicAdd(&out1[input_seq[l]], pc[l]);
}

// ---------------- k_log ----------------
__global__ __launch_bounds__(256) void k_log(float* __restrict__ out1)
{
    int i = blockIdx.x * 256 + threadIdx.x;
    float v = out1[i];
    if (i == 2 || v == 0.0f) v = 1e-9f;
    out1[i] = logf(v);
}

// ---------------- host launch ----------------
extern "C" void kernel_launch(void* const* d_in, const int* in_sizes, int n_in,
                              void* d_out, int out_size, void* d_ws, size_t ws_size,
                              hipStream_t stream) {
    const int*   inp       = (const int*)  d_in[0];
    const float* hidden    = (const float*)d_in[1];
    const float* enc       = (const float*)d_in[2];
    const int*   input_seq = (const int*)  d_in[3];
    const int*   pre_prob  = (const int*)  d_in[4];
    const float* emb       = (const float*)d_in[5];
    const float* attn_W    = (const float*)d_in[6];
    const float* attn_b    = (const float*)d_in[7];
    const float* comb_W    = (const float*)d_in[8];
    const float* comb_b    = (const float*)d_in[9];
    const float* W_ih      = (const float*)d_in[10];
    const float* W_hh      = (const float*)d_in[11];
    const float* b_ih      = (const float*)d_in[12];
    const float* b_hh      = (const float*)d_in[13];
    const float* Wo_W      = (const float*)d_in[14];
    const float* Wo_b      = (const float*)d_in[15];
    const float* Wc_W      = (const float*)d_in[16];
    const float* Wc_b      = (const float*)d_in[17];

    float* out = (float*)d_out;

    // ws layout: [Ah 2M us][Al 2M us][Bh 1M us][Bl 1M us][P 2*2M f][smalls]
    unsigned short* Ah = (unsigned short*)d_ws;
    unsigned short* Al = Ah + (size_t)LQ * EQ;
    unsigned short* Bh = Al + (size_t)LQ * EQ;
    unsigned short* Bl = Bh + (size_t)HQ * EQ;
    float* P      = (float*)(Bl + (size_t)HQ * EQ);
    float* x2     = P + 2 * (size_t)PSZ;   // 2048 (comb out | sel_reading)
    float* hnew   = x2 + 2048;             // 1024
    float* logits = hnew + 1024;           // 2048
    float* aa     = logits + 2048;         // 1024
    float* score  = aa + 1024;             // 34048

    k_split_prep<<<1537, 256, 0, stream>>>(enc, Wc_W, inp, input_seq, pre_prob,
                                           Ah, Al, Bh, Bl, x2);
    k_gemm_mfma<<<dim3(HQ / 128, LQ / 128, 2), 256, 0, stream>>>(Ah, Al, Bh, Bl,
                                                                 P);
    k_attn<<<LQ / 4, 256, 0, stream>>>(attn_W, attn_b, inp, emb, hidden,
                                       logits, aa);
    k_attn_sm_apply<<<dim3(EQ / 256, 16), 256, 0, stream>>>(logits, enc, aa,
                                                            out + AW_OFF);
    k_comb<<<HQ / 4, 256, 0, stream>>>(comb_W, comb_b, inp, emb, aa, x2);
    k_gru<<<HQ / 4, 256, 0, stream>>>(W_ih, W_hh, b_ih, b_hh, x2, hidden,
                                      hnew, out + HNEW_OFF);
    k_scores<<<(VQ + LQ) / 4, 256, 0, stream>>>(Wo_W, Wo_b, P, Wc_b, hnew,
                                                score);
    k_probs<<<(MVQ + LQ) / 256, 256, 0, stream>>>(score, out + OUT1_OFF,
                                                  out + PC_OFF);
    k_scatter<<<LQ / 256, 256, 0, stream>>>(input_seq, out + PC_OFF,
                                            out + OUT1_OFF);
    k_log<<<MVQ / 256, 256, 0, stream>>>(out + OUT1_OFF);
}

// Round 5
// 123.950 us; speedup vs baseline: 1.3089x; 1.0634x over previous
//
#include <hip/hip_runtime.h>
#include <math.h>

#define LQ 2048
#define EQ 1024
#define HQ 1024
#define DQ 512
#define VQ 32000
#define MVQ 32768

// d_out layout (floats): [out1: 32768][h_new: 1024][attn_w: 2048][prob_c: 2048]
#define OUT1_OFF 0
#define HNEW_OFF 32768
#define AW_OFF   33792
#define PC_OFF   35840

#define PSZ 2097152  // one K-split partial: 2048x1024 floats
#define KSPLIT 4

typedef __attribute__((ext_vector_type(8))) short short8_t;
typedef __attribute__((ext_vector_type(8))) unsigned short ushort8_t;
typedef __attribute__((ext_vector_type(4))) float floatx4;

// ---------------- helpers ----------------
__device__ inline float wred(float v) {
    v += __shfl_down(v, 32);
    v += __shfl_down(v, 16);
    v += __shfl_down(v, 8);
    v += __shfl_down(v, 4);
    v += __shfl_down(v, 2);
    v += __shfl_down(v, 1);
    return v;
}
__device__ inline float wred_max(float v) {
    v = fmaxf(v, __shfl_down(v, 32));
    v = fmaxf(v, __shfl_down(v, 16));
    v = fmaxf(v, __shfl_down(v, 8));
    v = fmaxf(v, __shfl_down(v, 4));
    v = fmaxf(v, __shfl_down(v, 2));
    v = fmaxf(v, __shfl_down(v, 1));
    return v;
}
__device__ inline float sigmoidf_(float x) { return 1.0f / (1.0f + expf(-x)); }
__device__ inline unsigned short f2bf(float x) {  // RNE to bf16 bits
    unsigned int u = __float_as_uint(x);
    unsigned int r = (u + 0x7fffu + ((u >> 16) & 1u)) >> 16;
    return (unsigned short)r;
}
__device__ inline float bf2f(unsigned short b) {
    return __uint_as_float(((unsigned int)b) << 16);
}
// async global->LDS, 16B per lane; LDS dest is wave-uniform base + lane*16
__device__ __forceinline__ void gload16(const unsigned short* g,
                                        unsigned short* l) {
    __builtin_amdgcn_global_load_lds(
        (const __attribute__((address_space(1))) unsigned int*)g,
        (__attribute__((address_space(3))) unsigned int*)l, 16, 0, 0);
}

// ---------------- k_prep ----------------
// blocks 0..511   : attn logits (4 rows/block); blocks 0..3 also zero aa
// block  512      : sel_reading (exact int32 truncation) -> x2[1024:2048)
// blocks 513..2048: split enc (2M) then Wc (1M) into bf16 hi/lo
__global__ __launch_bounds__(256) void k_prep(
    const float* __restrict__ enc, const float* __restrict__ Wc,
    const int* __restrict__ inp, const int* __restrict__ input_seq,
    const int* __restrict__ pre_prob,
    const float* __restrict__ attn_W, const float* __restrict__ attn_b,
    const float* __restrict__ emb, const float* __restrict__ hidden,
    unsigned short* __restrict__ Ah, unsigned short* __restrict__ Al,
    unsigned short* __restrict__ Bh, unsigned short* __restrict__ Bl,
    float* __restrict__ x2, float* __restrict__ logits, float* __restrict__ aa)
{
    __shared__ int s_cnt;
    __shared__ int s_list[LQ];
    const int tid = threadIdx.x;
    const int bx = blockIdx.x;
    if (bx < 512) {  // ---- attn logits ----
        if (bx < 4) aa[bx * 256 + tid] = 0.0f;
        int warp = tid >> 6, lane = tid & 63;
        int r = bx * 4 + warp;
        int tok = inp[0];
        int ei = (tok >= VQ) ? 2 : tok;
        const float4* Wr = (const float4*)(attn_W + (size_t)r * 1536);
        const float4* e4 = (const float4*)(emb + (size_t)ei * DQ);
        const float4* h4 = (const float4*)hidden;
        float acc = 0.0f;
        #pragma unroll
        for (int i = 0; i < 6; ++i) {
            int idx = lane + i * 64;
            float4 x = (idx < 128) ? e4[idx] : h4[idx - 128];
            float4 w = Wr[idx];
            acc += w.x * x.x + w.y * x.y + w.z * x.z + w.w * x.w;
        }
        acc = wred(acc);
        if (lane == 0) logits[r] = acc + attn_b[r];
        return;
    }
    if (bx == 512) {  // ---- sel_reading ----
        if (tid == 0) s_cnt = 0;
        __syncthreads();
        int tok = inp[0];
        for (int l = tid; l < LQ; l += 256) {
            if (input_seq[l] == tok && pre_prob[l] != 0) {
                int p = atomicAdd(&s_cnt, 1);
                s_list[p] = l;
            }
        }
        __syncthreads();
        int nm = s_cnt;
        for (int e = tid; e < EQ; e += 256) {
            int acc = 0;
            for (int j = 0; j < nm; ++j)
                acc += (int)enc[(size_t)s_list[j] * EQ + e];
            x2[HQ + e] = (float)acc;
        }
        return;
    }
    // ---- bf16 hi/lo split ----
    size_t e0 = ((size_t)(bx - 513) * 256 + tid) * 8;
    const float* src;
    unsigned short *hdst, *ldst;
    size_t off;
    if (e0 < (size_t)LQ * EQ) { src = enc; hdst = Ah; ldst = Al; off = e0; }
    else { src = Wc; hdst = Bh; ldst = Bl; off = e0 - (size_t)LQ * EQ; }
    float4 v0 = *(const float4*)(src + off);
    float4 v1 = *(const float4*)(src + off + 4);
    float vv[8] = {v0.x, v0.y, v0.z, v0.w, v1.x, v1.y, v1.z, v1.w};
    ushort8_t H, L;
    #pragma unroll
    for (int k = 0; k < 8; ++k) {
        float x = vv[k];
        unsigned short hb = f2bf(x);
        H[k] = hb;
        L[k] = f2bf(x - bf2f(hb));  // exact residual
    }
    *(ushort8_t*)(hdst + off) = H;
    *(ushort8_t*)(ldst + off) = L;
}

// ---------------- k_gemm_mfma ----------------
// P_z = enc_slice @ Wc^T_slice via 3-term bf16 split (hi*hi + lo*hi + hi*lo).
// m97 structure: global_load_lds(16B) staging, linear LDS + source-side XOR
// swizzle, BK=64, 128x128 tile, K-split z in 0..3 (K=256 each) -> grid 512
// blocks = 2 blocks/CU (64KB LDS), 2 waves/SIMD for stall interleaving.
__global__ __launch_bounds__(256, 2) void k_gemm_mfma(
    const unsigned short* __restrict__ Ah, const unsigned short* __restrict__ Al,
    const unsigned short* __restrict__ Bh, const unsigned short* __restrict__ Bl,
    float* __restrict__ P)
{
    __shared__ unsigned short sm[4 * 8192];  // 4 tiles x 128rows x 64 bf16
    const int t = threadIdx.x;
    const int lane = t & 63, wid = t >> 6;
    const int n0 = blockIdx.x * 128;
    const int m0 = blockIdx.y * 128;
    const int kz = blockIdx.z * 256;  // K element offset of this slice
    float* Pz = P + (size_t)blockIdx.z * PSZ;

    const unsigned short* tsrc =
        (wid == 0) ? Ah + (size_t)m0 * EQ :
        (wid == 1) ? Al + (size_t)m0 * EQ :
        (wid == 2) ? Bh + (size_t)n0 * EQ :
                     Bl + (size_t)n0 * EQ;
    unsigned short* tdst = sm + wid * 8192;

    const int srow = lane >> 3;   // row within 8-row staging call
    const int schunk = lane & 7;  // 16B chunk within row
    const int wm = (wid >> 1) * 64, wn = (wid & 1) * 64;
    const int fr = lane & 15, kg = lane >> 4;

    floatx4 acc[4][4];
    #pragma unroll
    for (int i = 0; i < 4; ++i)
        #pragma unroll
        for (int j = 0; j < 4; ++j)
            acc[i][j] = (floatx4){0.f, 0.f, 0.f, 0.f};

    for (int s = 0; s < 4; ++s) {
        // ---- stage: 16 async 1KB calls; LDS linear, source pre-swizzled ----
        #pragma unroll
        for (int c = 0; c < 16; ++c) {
            int row = c * 8 + srow;
            int gch = schunk ^ (row & 7);
            gload16(tsrc + (size_t)row * EQ + kz + s * 64 + gch * 8,
                    tdst + c * 512);
        }
        __syncthreads();  // compiler drains vmcnt(0) before barrier
        // ---- compute: 2 K-halves x 16 frag-pairs x 3 terms = 96 MFMA ----
        #pragma unroll
        for (int kk = 0; kk < 2; ++kk) {
            short8_t fah[4], fal[4], fbh[4], fbl[4];
            #pragma unroll
            for (int f = 0; f < 4; ++f) {
                int rowa = wm + f * 16 + fr;
                int ba = rowa * 128 + ((kk * 4 + kg) ^ (rowa & 7)) * 16;
                fah[f] = *(const short8_t*)((const char*)sm + ba);
                fal[f] = *(const short8_t*)((const char*)sm + 16384 + ba);
                int rowb = wn + f * 16 + fr;
                int bb = rowb * 128 + ((kk * 4 + kg) ^ (rowb & 7)) * 16;
                fbh[f] = *(const short8_t*)((const char*)sm + 32768 + bb);
                fbl[f] = *(const short8_t*)((const char*)sm + 49152 + bb);
            }
            #pragma unroll
            for (int i = 0; i < 4; ++i)
                #pragma unroll
                for (int j = 0; j < 4; ++j) {
                    acc[i][j] = __builtin_amdgcn_mfma_f32_16x16x32_bf16(
                        fah[i], fbh[j], acc[i][j], 0, 0, 0);
                    acc[i][j] = __builtin_amdgcn_mfma_f32_16x16x32_bf16(
                        fal[i], fbh[j], acc[i][j], 0, 0, 0);
                    acc[i][j] = __builtin_amdgcn_mfma_f32_16x16x32_bf16(
                        fah[i], fbl[j], acc[i][j], 0, 0, 0);
                }
        }
        __syncthreads();
    }
    // C/D layout: col = lane&15, row = (lane>>4)*4 + reg  [m89-verified]
    #pragma unroll
    for (int i = 0; i < 4; ++i)
        #pragma unroll
        for (int j = 0; j < 4; ++j) {
            int row = m0 + wm + i * 16 + kg * 4;
            int col = n0 + wn + j * 16 + fr;
            #pragma unroll
            for (int r = 0; r < 4; ++r)
                Pz[(size_t)(row + r) * HQ + col] = acc[i][j][r];
        }
}

// ---------------- k_attn_sm_apply ----------------
// Per-block softmax stats (identical across blocks), write aw, aa += w.enc
__global__ __launch_bounds__(256) void k_attn_sm_apply(
    const float* __restrict__ logits, const float* __restrict__ enc,
    float* __restrict__ aa, float* __restrict__ aw_out)
{
    __shared__ float sred[4];
    __shared__ float s_w[128];
    int tid = threadIdx.x, wid = tid >> 6, lane = tid & 63;
    float m = -3.4e38f;
    for (int i = tid; i < LQ; i += 256) m = fmaxf(m, logits[i]);
    m = wred_max(m);
    if (lane == 0) sred[wid] = m;
    __syncthreads();
    if (tid == 0)
        sred[0] = fmaxf(fmaxf(sred[0], sred[1]), fmaxf(sred[2], sred[3]));
    __syncthreads();
    m = sred[0];
    __syncthreads();
    float s = 0.0f;
    for (int i = tid; i < LQ; i += 256) s += expf(logits[i] - m);
    s = wred(s);
    if (lane == 0) sred[wid] = s;
    __syncthreads();
    if (tid == 0) sred[0] = sred[0] + sred[1] + sred[2] + sred[3];
    __syncthreads();
    s = sred[0];
    int l0 = blockIdx.y * 128;
    if (tid < 128) {
        float w = expf(logits[l0 + tid] - m) / s;
        s_w[tid] = w;
        if (blockIdx.x == 0) aw_out[l0 + tid] = w;
    }
    __syncthreads();
    int e = blockIdx.x * 256 + tid;
    float acc = 0.0f;
    for (int l = 0; l < 128; ++l)
        acc = fmaf(s_w[l], enc[(size_t)(l0 + l) * EQ + e], acc);
    atomicAdd(&aa[e], acc);
}

// ---------------- k_comb ----------------
__global__ __launch_bounds__(256) void k_comb(
    const float* __restrict__ W, const float* __restrict__ b,
    const int* __restrict__ inp, const float* __restrict__ emb,
    const float* __restrict__ aa, float* __restrict__ x2)
{
    int warp = threadIdx.x >> 6, lane = threadIdx.x & 63;
    int r = blockIdx.x * 4 + warp;
    int tok = inp[0];
    int ei = (tok >= VQ) ? 2 : tok;
    const float4* Wr = (const float4*)(W + (size_t)r * 1536);
    const float4* e4 = (const float4*)(emb + (size_t)ei * DQ);
    const float4* a4 = (const float4*)aa;
    float acc = 0.0f;
    #pragma unroll
    for (int i = 0; i < 6; ++i) {
        int idx = lane + i * 64;
        float4 x = (idx < 128) ? e4[idx] : a4[idx - 128];
        float4 w = Wr[idx];
        acc += w.x * x.x + w.y * x.y + w.z * x.z + w.w * x.w;
    }
    acc = wred(acc);
    if (lane == 0) x2[r] = fmaxf(acc + b[r], 0.0f);
}

// ---------------- k_gru ----------------
// Fused: warp handles gate index i; computes all 6 dots, gates, h_new.
__global__ __launch_bounds__(256) void k_gru(
    const float* __restrict__ W_ih, const float* __restrict__ W_hh,
    const float* __restrict__ b_ih, const float* __restrict__ b_hh,
    const float* __restrict__ x2, const float* __restrict__ h,
    float* __restrict__ hnew, float* __restrict__ out_h)
{
    int warp = threadIdx.x >> 6, lane = threadIdx.x & 63;
    int i = blockIdx.x * 4 + warp;
    const float4* xv = (const float4*)x2;
    const float4* hv = (const float4*)h;
    const float4* Wr = (const float4*)(W_ih + (size_t)i * 2048);
    const float4* Wz = (const float4*)(W_ih + (size_t)(HQ + i) * 2048);
    const float4* Wn = (const float4*)(W_ih + (size_t)(2 * HQ + i) * 2048);
    const float4* Ur = (const float4*)(W_hh + (size_t)i * 1024);
    const float4* Uz = (const float4*)(W_hh + (size_t)(HQ + i) * 1024);
    const float4* Un = (const float4*)(W_hh + (size_t)(2 * HQ + i) * 1024);
    float ar = 0, az = 0, an = 0, br = 0, bz = 0, bn = 0;
    #pragma unroll
    for (int c = 0; c < 8; ++c) {
        int idx = lane + c * 64;
        float4 x = xv[idx];
        float4 w = Wr[idx]; ar += w.x*x.x + w.y*x.y + w.z*x.z + w.w*x.w;
        w = Wz[idx];        az += w.x*x.x + w.y*x.y + w.z*x.z + w.w*x.w;
        w = Wn[idx];        an += w.x*x.x + w.y*x.y + w.z*x.z + w.w*x.w;
    }
    #pragma unroll
    for (int c = 0; c < 4; ++c) {
        int idx = lane + c * 64;
        float4 x = hv[idx];
        float4 w = Ur[idx]; br += w.x*x.x + w.y*x.y + w.z*x.z + w.w*x.w;
        w = Uz[idx];        bz += w.x*x.x + w.y*x.y + w.z*x.z + w.w*x.w;
        w = Un[idx];        bn += w.x*x.x + w.y*x.y + w.z*x.z + w.w*x.w;
    }
    ar = wred(ar); az = wred(az); an = wred(an);
    br = wred(br); bz = wred(bz); bn = wred(bn);
    if (lane == 0) {
        float r = sigmoidf_(ar + b_ih[i] + br + b_hh[i]);
        float z = sigmoidf_(az + b_ih[HQ + i] + bz + b_hh[HQ + i]);
        float n = tanhf(an + b_ih[2 * HQ + i] + r * (bn + b_hh[2 * HQ + i]));
        float hn = (1.0f - z) * n + z * h[i];
        hnew[i] = hn;
        out_h[i] = hn;
    }
}

// ---------------- k_scores ----------------
// r < VQ:  score[r] = Wo_W[r,:] . hnew + Wo_b[r]
// r >= VQ: l=r-VQ: score[VQ+l] = sum_h tanh(sum_z Pz[l][h] + Wc_b[h])*hnew[h]
__global__ __launch_bounds__(256) void k_scores(
    const float* __restrict__ Wo_W, const float* __restrict__ Wo_b,
    const float* __restrict__ P, const float* __restrict__ Wc_b,
    const float* __restrict__ hnew, float* __restrict__ score)
{
    int warp = threadIdx.x >> 6, lane = threadIdx.x & 63;
    int r = blockIdx.x * 4 + warp;
    const float4* hv = (const float4*)hnew;
    float acc = 0.0f;
    if (r < VQ) {
        const float4* Wr = (const float4*)(Wo_W + (size_t)r * HQ);
        #pragma unroll
        for (int i = 0; i < 4; ++i) {
            int idx = lane + i * 64;
            float4 w = Wr[idx], x = hv[idx];
            acc += w.x * x.x + w.y * x.y + w.z * x.z + w.w * x.w;
        }
        acc = wred(acc);
        if (lane == 0) score[r] = acc + Wo_b[r];
    } else {
        int l = r - VQ;
        const float4* P0 = (const float4*)(P + (size_t)l * HQ);
        const float4* P1 = (const float4*)(P + (size_t)PSZ + (size_t)l * HQ);
        const float4* P2 = (const float4*)(P + 2 * (size_t)PSZ + (size_t)l * HQ);
        const float4* P3 = (const float4*)(P + 3 * (size_t)PSZ + (size_t)l * HQ);
        #pragma unroll
        for (int i = 0; i < 4; ++i) {
            int idx = lane + i * 64;
            float4 a = P0[idx], b1 = P1[idx], b2 = P2[idx], b3 = P3[idx];
            float4 bb = *(const float4*)(Wc_b + idx * 4);
            float4 x = hv[idx];
            acc += tanhf(a.x + b1.x + b2.x + b3.x + bb.x) * x.x +
                   tanhf(a.y + b1.y + b2.y + b3.y + bb.y) * x.y +
                   tanhf(a.z + b1.z + b2.z + b3.z + bb.z) * x.z +
                   tanhf(a.w + b1.w + b2.w + b3.w + bb.w) * x.w;
        }
        acc = wred(acc);
        if (lane == 0) score[VQ + l] = acc;
    }
}

// ---------------- k_final ----------------
// Fused probs+scatter+log. 128 blocks; each block: recompute softmax stats
// (L2-resident score reads, deterministic & identical across blocks), then
// LDS-bin the prob_c scatter contributions for its 256-wide out1 slice,
// then write out1 = log(prob_g + scatter) with the 1e-9 rules.
// Blocks 0..7 also emit out_pc.
__global__ __launch_bounds__(256) void k_final(
    const float* __restrict__ score, const int* __restrict__ input_seq,
    float* __restrict__ out1, float* __restrict__ out_pc)
{
    __shared__ float sred[4];
    __shared__ float bins[256];
    const int N = VQ + LQ;
    int tid = threadIdx.x, wid = tid >> 6, lane = tid & 63;
    float m = -3.4e38f;
    for (int i = tid; i < N; i += 256) m = fmaxf(m, score[i]);
    m = wred_max(m);
    if (lane == 0) sred[wid] = m;
    __syncthreads();
    if (tid == 0)
        sred[0] = fmaxf(fmaxf(sred[0], sred[1]), fmaxf(sred[2], sred[3]));
    __syncthreads();
    m = sred[0];
    __syncthreads();
    float s = 0.0f;
    for (int i = tid; i < N; i += 256) s += expf(score[i] - m);
    s = wred(s);
    if (lane == 0) sred[wid] = s;
    __syncthreads();
    if (tid == 0) sred[0] = sred[0] + sred[1] + sred[2] + sred[3];
    __syncthreads();
    s = sred[0];
    bins[tid] = 0.0f;
    __syncthreads();
    int i0 = blockIdx.x * 256;
    for (int l = tid; l < LQ; l += 256) {
        int si = input_seq[l];
        if (si >= i0 && si < i0 + 256)
            atomicAdd(&bins[si - i0], expf(score[VQ + l] - m) / s);
    }
    if (blockIdx.x < 8) {
        int l = blockIdx.x * 256 + tid;
        out_pc[l] = expf(score[VQ + l] - m) / s;
    }
    __syncthreads();
    int i = i0 + tid;
    float v = ((i < VQ) ? expf(score[i] - m) / s : 0.0f) + bins[tid];
    if (i == 2 || v == 0.0f) v = 1e-9f;
    out1[i] = logf(v);
}

// ---------------- host launch ----------------
extern "C" void kernel_launch(void* const* d_in, const int* in_sizes, int n_in,
                              void* d_out, int out_size, void* d_ws, size_t ws_size,
                              hipStream_t stream) {
    const int*   inp       = (const int*)  d_in[0];
    const float* hidden    = (const float*)d_in[1];
    const float* enc       = (const float*)d_in[2];
    const int*   input_seq = (const int*)  d_in[3];
    const int*   pre_prob  = (const int*)  d_in[4];
    const float* emb       = (const float*)d_in[5];
    const float* attn_W    = (const float*)d_in[6];
    const float* attn_b    = (const float*)d_in[7];
    const float* comb_W    = (const float*)d_in[8];
    const float* comb_b    = (const float*)d_in[9];
    const float* W_ih      = (const float*)d_in[10];
    const float* W_hh      = (const float*)d_in[11];
    const float* b_ih      = (const float*)d_in[12];
    const float* b_hh      = (const float*)d_in[13];
    const float* Wo_W      = (const float*)d_in[14];
    const float* Wo_b      = (const float*)d_in[15];
    const float* Wc_W      = (const float*)d_in[16];
    const float* Wc_b      = (const float*)d_in[17];

    float* out = (float*)d_out;

    // ws: [Ah 2M us][Al 2M us][Bh 1M us][Bl 1M us][P 4*2M f][smalls]
    unsigned short* Ah = (unsigned short*)d_ws;
    unsigned short* Al = Ah + (size_t)LQ * EQ;
    unsigned short* Bh = Al + (size_t)LQ * EQ;
    unsigned short* Bl = Bh + (size_t)HQ * EQ;
    float* P      = (float*)(Bl + (size_t)HQ * EQ);
    float* x2     = P + (size_t)KSPLIT * PSZ;  // 2048 (comb out | sel_reading)
    float* hnew   = x2 + 2048;                 // 1024
    float* logits = hnew + 1024;               // 2048
    float* aa     = logits + 2048;             // 1024
    float* score  = aa + 1024;                 // 34048

    k_prep<<<2049, 256, 0, stream>>>(enc, Wc_W, inp, input_seq, pre_prob,
                                     attn_W, attn_b, emb, hidden,
                                     Ah, Al, Bh, Bl, x2, logits, aa);
    k_gemm_mfma<<<dim3(HQ / 128, LQ / 128, KSPLIT), 256, 0, stream>>>(
        Ah, Al, Bh, Bl, P);
    k_attn_sm_apply<<<dim3(EQ / 256, 16), 256, 0, stream>>>(logits, enc, aa,
                                                            out + AW_OFF);
    k_comb<<<HQ / 4, 256, 0, stream>>>(comb_W, comb_b, inp, emb, aa, x2);
    k_gru<<<HQ / 4, 256, 0, stream>>>(W_ih, W_hh, b_ih, b_hh, x2, hidden,
                                      hnew, out + HNEW_OFF);
    k_scores<<<(VQ + LQ) / 4, 256, 0, stream>>>(Wo_W, Wo_b, P, Wc_b, hnew,
                                                score);
    k_final<<<MVQ / 256, 256, 0, stream>>>(score, input_seq, out + OUT1_OFF,
                                           out + PC_OFF);
}